// Round 1
// baseline (2238.779 us; speedup 1.0000x reference)
//
#include <hip/hip_runtime.h>

// Sparse 3x3 conv, NCHW / OIHW, stride 1, pad 1, dil 1, fp32.
// B=32, CIN=COUT=256, H=W=56. ~90% of weights are exactly 0.
//
// Strategy (round 0, correctness-first):
//   1 block per (b, cout). Phase 1: deterministically compact this cout's
//   2304 weights into an LDS list of nonzeros {byte-offset-into-x, value}.
//   Phase 2: each thread computes output pixels; interior pixels (93%) use a
//   bounds-check-free inner loop; border pixels (220/plane) use a checked one.
//   Output-index remapping groups interior pixels so waves don't mix paths.

constexpr int BB   = 32;
constexpr int CIN  = 256;
constexpr int COUT = 256;
constexpr int H    = 56;
constexpr int W    = 56;
constexpr int HW   = H * W;          // 3136
constexpr int WSZ  = CIN * 9;        // 2304 weights per cout
constexpr int NIN  = 54 * 54;        // 2916 interior pixels
constexpr int NBOR = HW - NIN;       // 220 border pixels

__global__ __launch_bounds__(256)
void sparse_conv3x3(const float* __restrict__ x,
                    const float* __restrict__ wgt,
                    float* __restrict__ out) {
    const int bc   = blockIdx.x;      // b * COUT + cout
    const int cout = bc % COUT;
    const int b    = bc / COUT;
    const int tid  = threadIdx.x;

    __shared__ int2          s_ent[WSZ];   // {byte offset, float bits}
    __shared__ unsigned char s_kk[WSZ];    // kh | (kw<<4), for border path
    __shared__ int           s_cnt[257];

    // ---- Phase 1: deterministic compaction of nonzero weights ----
    // Thread t owns weight indices [9t, 9t+9) == all 9 taps of cin = t.
    const float* wc = wgt + (size_t)cout * WSZ;
    float mv[9];
    int cnt = 0;
    #pragma unroll
    for (int i = 0; i < 9; ++i) {
        mv[i] = wc[tid * 9 + i];
        if (mv[i] != 0.0f) cnt++;
    }
    s_cnt[tid] = cnt;
    __syncthreads();
    if (tid == 0) {                    // cheap serial exclusive prefix (256 iters)
        int run = 0;
        for (int t = 0; t < 256; ++t) { int c = s_cnt[t]; s_cnt[t] = run; run += c; }
        s_cnt[256] = run;
    }
    __syncthreads();
    {
        int pos = s_cnt[tid];
        const int cin = tid;
        #pragma unroll
        for (int i = 0; i < 9; ++i) {
            if (mv[i] != 0.0f) {
                const int kh = i / 3, kw = i - kh * 3;
                int2 e;
                e.x = (cin * HW + (kh - 1) * W + (kw - 1)) * 4;  // byte offset
                e.y = __float_as_int(mv[i]);
                s_ent[pos] = e;
                s_kk[pos]  = (unsigned char)(kh | (kw << 4));
                pos++;
            }
        }
    }
    __syncthreads();
    const int nnz = s_cnt[256];

    const char* xb = (const char*)(x + (size_t)b * CIN * HW);
    float*      ob = out + (size_t)bc * HW;

    // ---- Phase 2: compute outputs. o is a remapped pixel index: ----
    //   o in [0, NIN)      -> interior pixel (h,w) = (1+o/54, 1+o%54)
    //   o in [NIN, HW)     -> border pixel
    for (int o = tid; o < HW; o += 256) {
        int h, w;
        bool interior = (o < NIN);
        if (interior) {
            h = 1 + o / 54;
            w = 1 + (o - (h - 1) * 54);
        } else {
            int o2 = o - NIN;
            if (o2 < 56)       { h = 0;  w = o2; }
            else if (o2 < 112) { h = 55; w = o2 - 56; }
            else if (o2 < 166) { h = 1 + (o2 - 112); w = 0; }
            else               { h = 1 + (o2 - 166); w = 55; }
        }

        const char* pb = xb + (size_t)(h * W + w) * 4;
        float acc = 0.0f;

        if (interior) {
            #pragma unroll 4
            for (int e = 0; e < nnz; ++e) {
                const int2 en = s_ent[e];
                acc = fmaf(__int_as_float(en.y),
                           *(const float*)(pb + en.x), acc);
            }
        } else {
            const int h1 = h - 1, w1 = w - 1;
            for (int e = 0; e < nnz; ++e) {
                const int2 en = s_ent[e];
                const int kk = s_kk[e];
                const int hh = h1 + (kk & 15);
                const int ww = w1 + (kk >> 4);
                if ((unsigned)hh < (unsigned)H && (unsigned)ww < (unsigned)W)
                    acc = fmaf(__int_as_float(en.y),
                               *(const float*)(pb + en.x), acc);
            }
        }
        ob[h * W + w] = acc;
    }
}

extern "C" void kernel_launch(void* const* d_in, const int* in_sizes, int n_in,
                              void* d_out, int out_size, void* d_ws, size_t ws_size,
                              hipStream_t stream) {
    const float* x = (const float*)d_in[0];
    const float* w = (const float*)d_in[1];
    float* out     = (float*)d_out;

    dim3 grid(BB * COUT);   // 8192 blocks, one per (b, cout)
    dim3 block(256);
    sparse_conv3x3<<<grid, block, 0, stream>>>(x, w, out);
}

// Round 2
// 177.177 us; speedup vs baseline: 12.6358x; 12.6358x over previous
//
#include <hip/hip_runtime.h>
#include <hip/hip_bf16.h>

// Sparse(=dense bf16 MFMA) 3x3 conv, NCHW/OIHW, stride1 pad1, fp32 in/out.
// B=32, CIN=COUT=256, H=W=56.
//
// R2: implicit-GEMM with mfma_f32_16x16x32_bf16.
//  prep_xp: x (fp32 NCHW) -> xp bf16 channels-last zero-padded [b][58][58][256]
//  prep_wb: w (OIHW fp32) -> wb bf16 [cout][tap][cin]
//  conv_mfma: block = 128 couts x 112 pixels (2 output rows of one b), 4 waves.
//    K-loop: 8 cin-blocks(32) x 9 taps; x-tile staged once per cin-block,
//    reused by all 9 taps (tap = LDS address offset). Weight tile per tap.
// Fallback to the R1 fp32 sparse kernel if d_ws is too small.

typedef __attribute__((ext_vector_type(8))) short short8;
typedef __attribute__((ext_vector_type(4))) float f32x4;
typedef __attribute__((ext_vector_type(4))) int i32x4;

constexpr int BB = 32, CIN = 256, COUT = 256, H = 56, W = 56, HW = H * W;
constexpr int HP = 58, WP = 58;          // padded spatial
constexpr int XSTR = 40, WSTR = 40;      // LDS cin stride (32 padded to 40 elems = 80B)

constexpr size_t XP_ELEMS = (size_t)BB * HP * WP * CIN;   // bf16 elems
constexpr size_t WB_ELEMS = (size_t)COUT * 9 * CIN;       // bf16 elems
constexpr size_t WS_NEEDED = (XP_ELEMS + WB_ELEMS) * 2;   // bytes

__device__ __forceinline__ ushort f2bf(float f) {
    unsigned x = __float_as_uint(f);
    unsigned r = (x + 0x7FFFu + ((x >> 16) & 1u)) >> 16;   // RNE
    return (ushort)r;
}

// ---------------- prep kernels ----------------

__global__ __launch_bounds__(256)
void prep_xp(const float* __restrict__ x, ushort* __restrict__ xp) {
    const int bi = blockIdx.x;            // b*58 + padded row i
    const int b = bi / HP, i = bi % HP;
    ushort* dst = xp + (size_t)bi * WP * CIN;
    const int t = threadIdx.x;            // cin
    if (i == 0 || i == HP - 1) {
        for (int c = 0; c < WP; ++c) dst[c * CIN + t] = 0;
    } else {
        const float* src = x + ((size_t)b * CIN + t) * HW + (size_t)(i - 1) * W;
        dst[0 * CIN + t] = 0;
        dst[(WP - 1) * CIN + t] = 0;
        for (int c = 1; c <= W; ++c)
            dst[c * CIN + t] = f2bf(src[c - 1]);
    }
}

__global__ __launch_bounds__(256)
void prep_wb(const float* __restrict__ w, ushort* __restrict__ wb) {
    const int d = blockIdx.x * 256 + threadIdx.x;  // dst index: (cout*9+tap)*256+cin
    const int cin = d & 255;
    const int rest = d >> 8;
    const int tap = rest % 9;
    const int cout = rest / 9;
    wb[d] = f2bf(w[((size_t)cout * CIN + cin) * 9 + tap]);
}

// ---------------- MFMA conv ----------------

__global__ __launch_bounds__(256)
void conv_mfma(const ushort* __restrict__ xp, const ushort* __restrict__ wb,
               float* __restrict__ out) {
    // XCD-aware swizzle: 1792 blocks, 1792 % 8 == 0
    int bx = blockIdx.x;
    bx = (bx & 7) * 224 + (bx >> 3);

    const int mt = bx & 1;                 // 2 cout tiles of 128
    const int nt = bx >> 1;                // 896 = 32 b * 28 row-pairs
    const int b  = nt / 28;
    const int h0 = (nt % 28) * 2;          // first output row of the tile

    const int tid  = threadIdx.x;
    const int wv   = tid >> 6;             // wave 0..3 -> couts [32wv, 32wv+32)
    const int lane = tid & 63;
    const int ml   = lane & 15;
    const int g    = lane >> 4;

    __shared__ ushort xs[4 * WP * XSTR];   // [4 rows][58 cols][40], 18560 elems
    __shared__ ushort wt[128 * WSTR];      // [128 cout][40]

    // A fragment offsets (elem units): lane holds W[cout = base+ml][k = 8g..8g+7]
    const int aoff0 = (wv * 32 + ml) * WSTR + 8 * g;
    const int aoff1 = aoff0 + 16 * WSTR;
    // B fragment offsets: lane holds X[k = 8g..][pix = nf*16+ml]
    int boff[7];
    #pragma unroll
    for (int nf = 0; nf < 7; ++nf) {
        const int p = nf * 16 + ml;        // 0..111
        const int hl = (p >= 56) ? 1 : 0;
        const int wl = p - 56 * hl;
        boff[nf] = (hl * WP + wl) * XSTR + 8 * g;
    }

    f32x4 acc[2][7] = {};

    const size_t xp_base = (size_t)(b * HP + h0) * WP * CIN;

    for (int cb = 0; cb < 8; ++cb) {
        __syncthreads();
        // stage x-tile: 4 rows x 58 cols, 32 cins each (64B segments)
        if (tid < 4 * WP) {
            const int r = tid / WP, c = tid % WP;
            const i32x4* src = (const i32x4*)(xp + xp_base + (size_t)(r * WP + c) * CIN + cb * 32);
            ushort* d = &xs[(r * WP + c) * XSTR];
            #pragma unroll
            for (int i = 0; i < 4; ++i) *(i32x4*)(d + i * 8) = src[i];
        }
        // stage w-tile for tap 0
        {
            const int cout = tid >> 1, half = tid & 1;
            const i32x4* src = (const i32x4*)(wb + (size_t)((mt * 128 + cout) * 9 + 0) * CIN
                                              + cb * 32 + half * 16);
            ushort* d = &wt[cout * WSTR + half * 16];
            i32x4 v0 = src[0], v1 = src[1];
            *(i32x4*)d = v0; *(i32x4*)(d + 8) = v1;
        }
        __syncthreads();

        for (int tap = 0; tap < 9; ++tap) {
            const int kh = tap / 3, kw = tap % 3;
            const int toff = (kh * WP + kw) * XSTR;

            const short8 a0 = *(const short8*)&wt[aoff0];
            const short8 a1 = *(const short8*)&wt[aoff1];
            #pragma unroll
            for (int nf = 0; nf < 7; ++nf) {
                const short8 bf = *(const short8*)&xs[boff[nf] + toff];
                acc[0][nf] = __builtin_amdgcn_mfma_f32_16x16x32_bf16(a0, bf, acc[0][nf], 0, 0, 0);
                acc[1][nf] = __builtin_amdgcn_mfma_f32_16x16x32_bf16(a1, bf, acc[1][nf], 0, 0, 0);
            }

            if (tap < 8) {
                __syncthreads();   // everyone done reading wt for this tap
                const int cout = tid >> 1, half = tid & 1;
                const i32x4* src = (const i32x4*)(wb + (size_t)((mt * 128 + cout) * 9 + tap + 1) * CIN
                                                  + cb * 32 + half * 16);
                ushort* d = &wt[cout * WSTR + half * 16];
                i32x4 v0 = src[0], v1 = src[1];
                *(i32x4*)d = v0; *(i32x4*)(d + 8) = v1;
                __syncthreads();
            }
        }
    }

    // epilogue: D frag -> out.  D[row=4g+r][col=ml] per m89.
    float* ob = out + ((size_t)b * COUT + mt * 128 + wv * 32) * HW;
    #pragma unroll
    for (int fm = 0; fm < 2; ++fm)
        #pragma unroll
        for (int nf = 0; nf < 7; ++nf)
            #pragma unroll
            for (int r = 0; r < 4; ++r) {
                const int cout_l = fm * 16 + 4 * g + r;
                const int p = nf * 16 + ml;
                const int hh = (p >= 56) ? 1 : 0;
                const int ww = p - 56 * hh;
                ob[(size_t)cout_l * HW + (h0 + hh) * W + ww] = acc[fm][nf][r];
            }
}

// ---------------- R1 fallback (fp32 sparse direct) ----------------

constexpr int WSZ = CIN * 9;
constexpr int NIN = 54 * 54;

__global__ __launch_bounds__(256)
void sparse_conv3x3(const float* __restrict__ x,
                    const float* __restrict__ wgt,
                    float* __restrict__ out) {
    const int bc = blockIdx.x, cout = bc % COUT, b = bc / COUT;
    const int tid = threadIdx.x;
    __shared__ int2 s_ent[WSZ];
    __shared__ unsigned char s_kk[WSZ];
    __shared__ int s_cnt[257];
    const float* wc = wgt + (size_t)cout * WSZ;
    float mv[9]; int cnt = 0;
    #pragma unroll
    for (int i = 0; i < 9; ++i) { mv[i] = wc[tid * 9 + i]; if (mv[i] != 0.0f) cnt++; }
    s_cnt[tid] = cnt; __syncthreads();
    if (tid == 0) { int run = 0; for (int t = 0; t < 256; ++t) { int c = s_cnt[t]; s_cnt[t] = run; run += c; } s_cnt[256] = run; }
    __syncthreads();
    { int pos = s_cnt[tid];
      #pragma unroll
      for (int i = 0; i < 9; ++i) if (mv[i] != 0.0f) {
          const int kh = i / 3, kw = i - kh * 3;
          int2 e; e.x = (tid * HW + (kh - 1) * W + (kw - 1)) * 4; e.y = __float_as_int(mv[i]);
          s_ent[pos] = e; s_kk[pos] = (unsigned char)(kh | (kw << 4)); pos++; } }
    __syncthreads();
    const int nnz = s_cnt[256];
    const char* xb = (const char*)(x + (size_t)b * CIN * HW);
    float* ob = out + (size_t)bc * HW;
    for (int o = tid; o < HW; o += 256) {
        int h, w; bool interior = (o < NIN);
        if (interior) { h = 1 + o / 54; w = 1 + (o - (h - 1) * 54); }
        else { int o2 = o - NIN;
            if (o2 < 56) { h = 0; w = o2; } else if (o2 < 112) { h = 55; w = o2 - 56; }
            else if (o2 < 166) { h = 1 + (o2 - 112); w = 0; } else { h = 1 + (o2 - 166); w = 55; } }
        const char* pb = xb + (size_t)(h * W + w) * 4;
        float acc = 0.0f;
        if (interior) {
            #pragma unroll 4
            for (int e = 0; e < nnz; ++e) { const int2 en = s_ent[e];
                acc = fmaf(__int_as_float(en.y), *(const float*)(pb + en.x), acc); }
        } else {
            const int h1 = h - 1, w1 = w - 1;
            for (int e = 0; e < nnz; ++e) { const int2 en = s_ent[e]; const int kk = s_kk[e];
                const int hh = h1 + (kk & 15), ww = w1 + (kk >> 4);
                if ((unsigned)hh < (unsigned)H && (unsigned)ww < (unsigned)W)
                    acc = fmaf(__int_as_float(en.y), *(const float*)(pb + en.x), acc); } }
        ob[h * W + w] = acc;
    }
}

// ---------------- launch ----------------

extern "C" void kernel_launch(void* const* d_in, const int* in_sizes, int n_in,
                              void* d_out, int out_size, void* d_ws, size_t ws_size,
                              hipStream_t stream) {
    const float* x = (const float*)d_in[0];
    const float* w = (const float*)d_in[1];
    float* out = (float*)d_out;

    if (ws_size >= WS_NEEDED) {
        ushort* xp = (ushort*)d_ws;
        ushort* wbp = xp + XP_ELEMS;
        prep_xp<<<BB * HP, 256, 0, stream>>>(x, xp);
        prep_wb<<<(int)(WB_ELEMS / 256), 256, 0, stream>>>(w, wbp);
        conv_mfma<<<1792, 256, 0, stream>>>(xp, wbp, out);
    } else {
        sparse_conv3x3<<<BB * COUT, 256, 0, stream>>>(x, w, out);
    }
}